// Round 7
// baseline (447.378 us; speedup 1.0000x reference)
//
#include <hip/hip_runtime.h>
#include <cstddef>

#define NSP   56
#define NPX   3136
#define CINN  32
#define COUTN 64
#define NB    128
#define CO_PB 8
#define ROWS  8              // output rows per strip
#define NSTRIP 7             // 7 * 8 = 56
#define THR   256            // 4 waves; wave w owns strip-rows w and w+4
#define SROWS 10             // staged rows = ROWS + 2 halo
#define SCOL  60             // staged cols: 0=left halo, 1..56=data, 57=right halo, 58-59 pad

// ---- pass 0: transpose W [co][c][kh][kw] -> w2 [cog][kk][c][co8] ----
__global__ __launch_bounds__(256)
void wtrans(const float* __restrict__ W, float* __restrict__ w2)
{
    int idx = blockIdx.x * 256 + threadIdx.x;
    if (idx < COUTN * CINN * 9) {
        int co_l = idx & 7;
        int t    = idx >> 3;         // (cog*9 + kk)*32 + c
        int c    = t & 31;
        t >>= 5;                     // cog*9 + kk
        int kk   = t % 9;
        int cog  = t / 9;
        w2[idx] = W[(size_t)(cog * 8 + co_l) * (CINN * 9) + c * 9 + kk];
    }
}

// ---- pass 1: conv(+bias,relu) in XLA:CPU/Eigen rounding order, y + argmax ----
// LDS x layout: xs[(sr*SCOL + col)*32 + slot*4 + ci], channel quad q stored at
// slot = q ^ (col & 7)  (XOR swizzle -> ds_read_b128 conflict-free).
__global__ __launch_bounds__(THR, 2)
void conv_emul_pass1(const float* __restrict__ x,
                     const float* __restrict__ w2,   // [8][9][32][8]
                     const float* __restrict__ bias,
                     float* __restrict__ y,          // d_out: relu(conv+bias)
                     int* __restrict__ amax)         // [NB*COUTN] argmax idx
{
    __shared__ float xs[SROWS * SCOL * 32];   // 76800 B
    __shared__ float rv[4][CO_PB];
    __shared__ int   ri[4][CO_PB];

    const int tid = threadIdx.x;
    const int wv  = tid >> 6;          // wave 0..3
    const int tx  = tid & 63;          // lane: col for staging, out-col for compute
    const int b       = blockIdx.x >> 3;
    const int cog     = blockIdx.x & 7;
    const int co_base = cog * CO_PB;

    const float* xb = x  + (size_t)b * CINN * NPX;
    const float* wq = w2 + (size_t)cog * (9 * CINN * CO_PB);  // uniform

    float bs[CO_PB];
    #pragma unroll
    for (int co = 0; co < CO_PB; ++co) bs[co] = bias[co_base + co];

    float v1[CO_PB]; int i1[CO_PB];
    #pragma unroll
    for (int co = 0; co < CO_PB; ++co) { v1[co] = -1.f; i1[co] = 0; }

    float* yo = y + (size_t)(b * COUTN + co_base) * NPX;

    #pragma unroll 1
    for (int g = 0; g < NSTRIP; ++g) {
        if (g) __syncthreads();        // WAR on xs

        // ---- stage rows 8g-1 .. 8g+8 (10 rows), swizzled c-contiguous ----
        #pragma unroll 1
        for (int sr = 0; sr < SROWS; ++sr) {
            int gr = 8 * g + sr - 1;
            int gc = tx - 1;
            bool vr = (unsigned)gr < (unsigned)NSP;
            bool vc = (unsigned)gc < (unsigned)NSP;
            #pragma unroll
            for (int t = 0; t < 2; ++t) {
                int qq = wv + 4 * t;                 // c-quad 0..7
                float4 v = make_float4(0.f, 0.f, 0.f, 0.f);
                if (vr && vc) {
                    const float* xp = xb + (size_t)(qq * 4) * NPX + gr * NSP + gc;
                    v.x = xp[0];
                    v.y = xp[NPX];
                    v.z = xp[2 * NPX];
                    v.w = xp[3 * NPX];
                }
                if (tx < SCOL) {
                    int s = qq ^ (tx & 7);
                    *(float4*)&xs[(sr * SCOL + tx) * 32 + s * 4] = v;
                }
            }
        }
        __syncthreads();

        float acc0[CO_PB], acc1[CO_PB];
        #pragma unroll
        for (int co = 0; co < CO_PB; ++co) { acc0[co] = 0.f; acc1[co] = 0.f; }

        if (tx < NSP) {
            // EXACT ref rounding order per pixel: kh -> kw -> c (c ascending),
            // single f32 acc, fmaf per term; padding terms are staged zeros.
            #pragma unroll
            for (int kh = 0; kh < 3; ++kh) {
                #pragma unroll
                for (int kw = 0; kw < 3; ++kw) {
                    const int col = tx + kw;                 // 0..57
                    const int cs  = col & 7;
                    const int base0 = ((wv + kh)     * SCOL + col) * 32;
                    const int base1 = ((wv + 4 + kh) * SCOL + col) * 32;
                    const float* wk = wq + (kh * 3 + kw) * (CINN * CO_PB);
                    #pragma unroll
                    for (int q = 0; q < 8; ++q) {
                        int s = q ^ cs;
                        float4 a4 = *(const float4*)&xs[base0 + s * 4];
                        float4 b4 = *(const float4*)&xs[base1 + s * 4];
                        const float av[4] = { a4.x, a4.y, a4.z, a4.w };
                        const float bv[4] = { b4.x, b4.y, b4.z, b4.w };
                        #pragma unroll
                        for (int j = 0; j < 4; ++j) {
                            const float* wc = wk + (q * 4 + j) * CO_PB;
                            #pragma unroll
                            for (int co = 0; co < CO_PB; ++co) {
                                acc0[co] = fmaf(av[j], wc[co], acc0[co]);
                                acc1[co] = fmaf(bv[j], wc[co], acc1[co]);
                            }
                        }
                    }
                }
            }
            // px0 (row 8g+wv) FIRST, then px1 (row 8g+wv+4): keeps first-max idx
            int p0 = (8 * g + wv) * NSP + tx;
            int p1 = p0 + 4 * NSP;
            #pragma unroll
            for (int co = 0; co < CO_PB; ++co) {
                float v = acc0[co] + bs[co];             // separate f32 add
                v = fmaxf(v, 0.f);
                yo[(size_t)co * NPX + p0] = v;
                if (v > v1[co]) { v1[co] = v; i1[co] = p0; }
                float u = acc1[co] + bs[co];
                u = fmaxf(u, 0.f);
                yo[(size_t)co * NPX + p1] = u;
                if (u > v1[co]) { v1[co] = u; i1[co] = p1; }
            }
        }
    }

    // block argmax per co: lexicographic (max val, min idx)
    #pragma unroll
    for (int co = 0; co < CO_PB; ++co) {
        float bv = v1[co]; int bi = i1[co];
        #pragma unroll
        for (int off = 32; off > 0; off >>= 1) {
            float ov = __shfl_xor(bv, off);
            int   oi = __shfl_xor(bi, off);
            if (ov > bv || (ov == bv && oi < bi)) { bv = ov; bi = oi; }
        }
        if ((tid & 63) == 0) { rv[wv][co] = bv; ri[wv][co] = bi; }
    }
    __syncthreads();
    if (tid < CO_PB) {
        float bv = rv[0][tid]; int bi = ri[0][tid];
        #pragma unroll
        for (int w = 1; w < 4; ++w) {
            float ov = rv[w][tid]; int oi = ri[w][tid];
            if (ov > bv || (ov == bv && oi < bi)) { bv = ov; bi = oi; }
        }
        amax[b * COUTN + co_base + tid] = bi;
    }
}

// ---- pass 2: in-place mask apply using the real templates input ----
__global__ __launch_bounds__(256)
void mask_apply_pass2(float* __restrict__ y,
                      const float* __restrict__ tmpl,
                      const int* __restrict__ amax)
{
    const int bc = blockIdx.x;                    // (b*64+co)
    const int idx = amax[bc];
    const float4* tp = (const float4*)(tmpl + (size_t)idx * NPX);
    float4* yp = (float4*)(y + (size_t)bc * NPX);
    #pragma unroll 1
    for (int p = threadIdx.x; p < NPX / 4; p += 256) {
        float4 a = yp[p];
        float4 t = tp[p];
        a.x *= t.x; a.y *= t.y; a.z *= t.z; a.w *= t.w;
        a.x = a.x > 0.f ? a.x : 0.f;
        a.y = a.y > 0.f ? a.y : 0.f;
        a.z = a.z > 0.f ? a.z : 0.f;
        a.w = a.w > 0.f ? a.w : 0.f;
        yp[p] = a;
    }
}

extern "C" void kernel_launch(void* const* d_in, const int* in_sizes, int n_in,
                              void* d_out, int out_size, void* d_ws, size_t ws_size,
                              hipStream_t stream)
{
    (void)in_sizes; (void)n_in; (void)ws_size; (void)out_size;
    const float* x  = (const float*)d_in[0];
    const float* W  = (const float*)d_in[1];
    const float* bi = (const float*)d_in[2];
    const float* tm = (const float*)d_in[3];
    float* out = (float*)d_out;
    int*   amax = (int*)d_ws;                           // 32 KB
    float* w2   = (float*)((char*)d_ws + 32768);        // 72 KB

    hipLaunchKernelGGL(wtrans, dim3(72), dim3(256), 0, stream, W, w2);

    dim3 grid1(NB * (COUTN / CO_PB));   // 1024 blocks
    hipLaunchKernelGGL(conv_emul_pass1, grid1, dim3(THR), 0, stream,
                       x, w2, bi, out, amax);

    dim3 grid2(NB * COUTN);             // 8192 blocks
    hipLaunchKernelGGL(mask_apply_pass2, grid2, dim3(256), 0, stream,
                       out, tm, amax);
}